// Round 15
// baseline (98.388 us; speedup 1.0000x reference)
//
#include <hip/hip_runtime.h>

// Problem constants
#define B_    4
#define S_    2048
#define DM_   1024
#define DK_   64
#define SCALE_ 0.03125f   // 1024^-0.5  (reference scales by d_model^-0.5, not d_k)

typedef float        f32x4  __attribute__((ext_vector_type(4)));
typedef short        short8 __attribute__((ext_vector_type(8)));
typedef float        fltx4  __attribute__((ext_vector_type(4)));
typedef unsigned int uint2v __attribute__((ext_vector_type(2)));
typedef unsigned int uint4v __attribute__((ext_vector_type(4)));

// fp32 -> bf16, round-to-nearest-even
static __device__ __forceinline__ unsigned short f2bf(float f) {
  unsigned u = __float_as_uint(f);
  u += 0x7fffu + ((u >> 16) & 1u);
  return (unsigned short)(u >> 16);
}
static __device__ __forceinline__ uint2v pack4(float a, float b, float c, float d) {
  uint2v r;
  r.x = (unsigned)f2bf(a) | ((unsigned)f2bf(b) << 16);
  r.y = (unsigned)f2bf(c) | ((unsigned)f2bf(d) << 16);
  return r;
}

// ---------------------------------------------------------------------------
// Kernel 0: detect mask element width (int32 of {0,1} vs byte-packed bools).
// ---------------------------------------------------------------------------
__global__ void detect_kernel(const unsigned int* __restrict__ m, unsigned int* __restrict__ flag) {
  unsigned v = m[threadIdx.x];
  unsigned long long bad = __ballot(v > 1u);
  if (threadIdx.x == 0) flag[0] = (bad != 0ull) ? 1u : 0u;
}

// ---------------------------------------------------------------------------
// Kernel W: convert the 3 weight matrices to bf16 once. Wb: [which][64][1024].
// ---------------------------------------------------------------------------
__global__ __launch_bounds__(256) void wconv_kernel(
    const float* __restrict__ wq, const float* __restrict__ wk, const float* __restrict__ wv,
    unsigned short* __restrict__ Wb)
{
  const int idx   = blockIdx.x * 256 + threadIdx.x;
  const int which = idx >> 13;
  const int e     = idx & 8191;
  const float* __restrict__ w = (which == 0) ? wq : (which == 1) ? wk : wv;
  fltx4 v0 = *reinterpret_cast<const fltx4*>(w + (size_t)e * 8);
  fltx4 v1 = *reinterpret_cast<const fltx4*>(w + (size_t)e * 8 + 4);
  uint4v o;
  o.x = (unsigned)f2bf(v0.x) | ((unsigned)f2bf(v0.y) << 16);
  o.y = (unsigned)f2bf(v0.z) | ((unsigned)f2bf(v0.w) << 16);
  o.z = (unsigned)f2bf(v1.x) | ((unsigned)f2bf(v1.y) << 16);
  o.w = (unsigned)f2bf(v1.z) | ((unsigned)f2bf(v1.w) << 16);
  *reinterpret_cast<uint4v*>(Wb + (size_t)which * 65536 + (size_t)e * 8) = o;
}

// ---------------------------------------------------------------------------
// Kernel 1: pack mask to 1 bit/element (2 MB, L2-hot). Verified R2-T3.
// 32 waves/CU, ~6.1 TB/s — the TLP reference proj13 now matches.
// ---------------------------------------------------------------------------
__global__ __launch_bounds__(256) void maskpack_kernel(const unsigned char* __restrict__ mb,
                                                       const unsigned int* __restrict__ mi,
                                                       const unsigned int* __restrict__ flag,
                                                       unsigned int* __restrict__ mp) {
  const int w = blockIdx.x * 256 + threadIdx.x;
  unsigned out = 0;
  if (flag[0]) {
    const uint4v* p = reinterpret_cast<const uint4v*>(mb + (size_t)w * 32);
    uint4v a = p[0], b = p[1];
    unsigned ws0[8];
    ws0[0]=a.x; ws0[1]=a.y; ws0[2]=a.z; ws0[3]=a.w; ws0[4]=b.x; ws0[5]=b.y; ws0[6]=b.z; ws0[7]=b.w;
#pragma unroll
    for (int i = 0; i < 8; ++i) {
      unsigned v = ws0[i];
      out |= ((v & 0x000000ffu) ? 1u : 0u) << (i * 4 + 0);
      out |= ((v & 0x0000ff00u) ? 1u : 0u) << (i * 4 + 1);
      out |= ((v & 0x00ff0000u) ? 1u : 0u) << (i * 4 + 2);
      out |= ((v & 0xff000000u) ? 1u : 0u) << (i * 4 + 3);
    }
  } else {
    const uint4v* p = reinterpret_cast<const uint4v*>(mi + (size_t)w * 32);
#pragma unroll
    for (int i = 0; i < 8; ++i) {
      uint4v a = p[i];
      out |= (a.x ? 1u : 0u) << (i * 4 + 0);
      out |= (a.y ? 1u : 0u) << (i * 4 + 1);
      out |= (a.z ? 1u : 0u) << (i * 4 + 2);
      out |= (a.w ? 1u : 0u) << (i * 4 + 3);
    }
  }
  mp[w] = out;
}

// ---------------------------------------------------------------------------
// Kernel 2 (v13): phase-separated projection at FULL OCCUPANCY.
// R14 diagnosis: hipcc serializes per-wave loads (~2 in flight, VGPR<=72
// across 8 variants); maskpack still hits 6.1 TB/s because 32 waves/CU
// round-robin hide each other's serial chains. proj never exceeded ~10.
// Fix (parameter-domain on proj12+proj3 templates): 512-thread blocks
// (8 waves), LDS 40 KB -> exactly 4 blocks/CU = 32 waves/CU; per-wave
// serial chain halved to 8 loads. Wave wid = (colgrp = wid>>1, khalf =
// wid&1): 16 MFMAs over K=512, then R5-verified LDS f32 reduction over
// K-halves. Swizzle involution on both sides (rule #21).
//   D[m=g*4+j][n=colgrp*16+r16] (T1-verified layout)
// ---------------------------------------------------------------------------
__global__ __launch_bounds__(512) void proj13_kernel(
    const float* __restrict__ xq, const float* __restrict__ xk, const float* __restrict__ xv,
    const unsigned short* __restrict__ Wb,
    unsigned short* __restrict__ Qp, unsigned short* __restrict__ Kp, unsigned short* __restrict__ Vt)
{
  const int which = blockIdx.y;
  const float* __restrict__ x = (which == 0) ? xq : (which == 1) ? xk : xv;
  const int row0 = blockIdx.x * 16;
  const int tid = threadIdx.x, wid = tid >> 6;
  const int lane = tid & 63, g = lane >> 4, r16 = lane & 15;
  const int cgrp = wid >> 1, khalf = wid & 1;

  __shared__ __align__(16) unsigned short Xb[16 * 1024];   // [16 rows][1024 bf16], pitch 2048 B, swizzled
  __shared__ __align__(16) f32x4 red[4][2][64];            // [cgrp][khalf][lane], 8 KB

  // ---- phase 1: stream the 16x1024 f32 tile (64 KB), 8 loads/thread ----
#pragma unroll
  for (int i = 0; i < 8; ++i) {
    const int fi   = i * 2048 + tid * 4;          // float index in row-major tile
    const int row  = fi >> 10;
    const int colf = fi & 1023;
    fltx4 v = *reinterpret_cast<const fltx4*>(x + (size_t)(row0 + row) * DM_ + colf);
    const int cb   = colf * 2;
    const int addr = row * 2048 + (cb ^ ((row & 15) << 4));
    *reinterpret_cast<uint2v*>((char*)Xb + addr) = pack4(v.x, v.y, v.z, v.w);
  }
  __syncthreads();   // single barrier; buffer written once, read once

  // ---- phase 2: 16 MFMAs over this wave's K-half; W from L2-hot Wb ----
  f32x4 acc; acc.x = 0.f; acc.y = 0.f; acc.z = 0.f; acc.w = 0.f;
  const unsigned short* __restrict__ wb =
      Wb + (size_t)which * 65536 + (size_t)(cgrp * 16 + r16) * DM_ + khalf * 512 + g * 8;
#pragma unroll
  for (int kc = 0; kc < 16; ++kc) {
    const int cb = khalf * 1024 + kc * 64 + g * 16;
    const int ra = r16 * 2048 + (cb ^ ((r16 & 15) << 4));
    short8 a = *reinterpret_cast<const short8*>((const char*)Xb + ra);
    short8 w = *reinterpret_cast<const short8*>(wb + kc * 32);
    acc = __builtin_amdgcn_mfma_f32_16x16x32_bf16(a, w, acc, 0, 0, 0);
  }

  // ---- K-half reduction (proj3-verified LDS pattern, deterministic) ----
  red[cgrp][khalf][lane] = acc;
  __syncthreads();

  if (wid < 4) {
    f32x4 a0 = red[wid][0][lane];
    f32x4 a1 = red[wid][1][lane];
    f32x4 s; s.x = a0.x + a1.x; s.y = a0.y + a1.y; s.z = a0.z + a1.z; s.w = a0.w + a1.w;
    // store: row = row0 + g*4 + j, col n = wid*16 + r16
    if (which < 2) {
      unsigned short* __restrict__ dst = (which == 0) ? Qp : Kp;
#pragma unroll
      for (int j = 0; j < 4; ++j)
        dst[(size_t)(row0 + g * 4 + j) * DK_ + wid * 16 + r16] = f2bf(s[j]);
    } else {
      const int grow = row0 + g * 4;
      const int bb = grow >> 11, sin = grow & 2047;
      *reinterpret_cast<uint2v*>(Vt + (size_t)(bb * DK_ + wid * 16 + r16) * S_ + sin) =
          pack4(s.x, s.y, s.z, s.w);
    }
  }
}

// ---------------------------------------------------------------------------
// Kernel 3a: flash attention PARTIAL (split-S x4). EXACT R8-R14 body (verified).
// ---------------------------------------------------------------------------
__global__ __launch_bounds__(64) void attn_part_kernel(
    const unsigned short* __restrict__ Qp, const unsigned short* __restrict__ Kp,
    const unsigned short* __restrict__ Vt, const unsigned int* __restrict__ mp,
    float* __restrict__ pacc, float* __restrict__ pm, float* __restrict__ pl)
{
  const int lane = threadIdx.x;
  const int g = lane >> 4, r16 = lane & 15;
  const int bx = blockIdx.x;
  const int sp = bx >> 9;
  const int qw = bx & 511;
  const int b  = qw >> 7;
  const int q0 = (qw & 127) * 16;

  __shared__ __align__(16) unsigned short Kt[64][72];
  __shared__ __align__(16) unsigned short Vs[64][72];
  __shared__ __align__(16) unsigned short Pq[16][72];

  short8 aq0, aq1;
  {
    const unsigned short* qrow = Qp + (size_t)(b * S_ + q0 + r16) * DK_ + g * 8;
    aq0 = *reinterpret_cast<const short8*>(qrow);
    aq1 = *reinterpret_cast<const short8*>(qrow + 32);
  }

  float mrun[4], lsum[4], corr[4];
  f32x4 acc[4];
#pragma unroll
  for (int j = 0; j < 4; ++j) { mrun[j] = -3.0e38f; lsum[j] = 0.f; }
#pragma unroll
  for (int nf = 0; nf < 4; ++nf) { acc[nf].x = 0.f; acc[nf].y = 0.f; acc[nf].z = 0.f; acc[nf].w = 0.f; }

  const int srow_stage = lane >> 3, sgran = lane & 7;

  for (int st = sp * 8; st < sp * 8 + 8; ++st) {
    const int s0 = st * 64;
#pragma unroll
    for (int i = 0; i < 8; ++i) {
      int r = i * 8 + srow_stage;
      uint4v kv = *reinterpret_cast<const uint4v*>(Kp + (size_t)(b * S_ + s0 + r) * DK_ + sgran * 8);
      *reinterpret_cast<uint4v*>(&Kt[r][sgran * 8]) = kv;
      uint4v vv = *reinterpret_cast<const uint4v*>(Vt + (size_t)(b * DK_ + r) * S_ + s0 + sgran * 8);
      *reinterpret_cast<uint4v*>(&Vs[r][sgran * 8]) = vv;
    }
    unsigned long long mw[4];
#pragma unroll
    for (int j = 0; j < 4; ++j) {
      size_t widx = ((size_t)(b * S_ + q0 + g * 4 + j) * S_ + s0) >> 5;
      mw[j] = *reinterpret_cast<const unsigned long long*>(mp + widx);
    }
    __syncthreads();

    f32x4 sc[4];
#pragma unroll
    for (int nf = 0; nf < 4; ++nf) { sc[nf].x = 0.f; sc[nf].y = 0.f; sc[nf].z = 0.f; sc[nf].w = 0.f; }
#pragma unroll
    for (int nf = 0; nf < 4; ++nf) {
      short8 bk0 = *reinterpret_cast<const short8*>(&Kt[nf * 16 + r16][g * 8]);
      short8 bk1 = *reinterpret_cast<const short8*>(&Kt[nf * 16 + r16][32 + g * 8]);
      sc[nf] = __builtin_amdgcn_mfma_f32_16x16x32_bf16(aq0, bk0, sc[nf], 0, 0, 0);
      sc[nf] = __builtin_amdgcn_mfma_f32_16x16x32_bf16(aq1, bk1, sc[nf], 0, 0, 0);
    }
#pragma unroll
    for (int nf = 0; nf < 4; ++nf)
#pragma unroll
      for (int j = 0; j < 4; ++j) {
        float v = sc[nf][j] * SCALE_;
        sc[nf][j] = ((mw[j] >> (nf * 16 + r16)) & 1ull) ? 1e-9f : v;
      }
#pragma unroll
    for (int j = 0; j < 4; ++j) {
      float tm = fmaxf(fmaxf(sc[0][j], sc[1][j]), fmaxf(sc[2][j], sc[3][j]));
#pragma unroll
      for (int off = 1; off < 16; off <<= 1) tm = fmaxf(tm, __shfl_xor(tm, off));
      float mn = fmaxf(mrun[j], tm);
      corr[j] = __expf(mrun[j] - mn);
      mrun[j] = mn;
    }
#pragma unroll
    for (int nf = 0; nf < 4; ++nf)
#pragma unroll
      for (int j = 0; j < 4; ++j)
        sc[nf][j] = __expf(sc[nf][j] - mrun[j]);
#pragma unroll
    for (int j = 0; j < 4; ++j) {
      float rs = (sc[0][j] + sc[1][j]) + (sc[2][j] + sc[3][j]);
#pragma unroll
      for (int off = 1; off < 16; off <<= 1) rs += __shfl_xor(rs, off);
      lsum[j] = lsum[j] * corr[j] + rs;
    }
#pragma unroll
    for (int nf = 0; nf < 4; ++nf) {
      acc[nf].x *= corr[0]; acc[nf].y *= corr[1]; acc[nf].z *= corr[2]; acc[nf].w *= corr[3];
    }
#pragma unroll
    for (int nf = 0; nf < 4; ++nf)
#pragma unroll
      for (int j = 0; j < 4; ++j)
        Pq[g * 4 + j][nf * 16 + r16] = f2bf(sc[nf][j]);
    asm volatile("s_waitcnt lgkmcnt(0)" ::: "memory");

#pragma unroll
    for (int k2 = 0; k2 < 2; ++k2) {
      short8 pa = *reinterpret_cast<const short8*>(&Pq[r16][k2 * 32 + g * 8]);
#pragma unroll
      for (int nf = 0; nf < 4; ++nf) {
        short8 bv = *reinterpret_cast<const short8*>(&Vs[nf * 16 + r16][k2 * 32 + g * 8]);
        acc[nf] = __builtin_amdgcn_mfma_f32_16x16x32_bf16(pa, bv, acc[nf], 0, 0, 0);
      }
    }
    __syncthreads();
  }

  float* __restrict__ pa = pacc + (size_t)(sp * 512 + qw) * 1024;
#pragma unroll
  for (int nf = 0; nf < 4; ++nf)
#pragma unroll
    for (int j = 0; j < 4; ++j)
      pa[(g * 4 + j) * 64 + nf * 16 + r16] = acc[nf][j];
  if (r16 == 0) {
#pragma unroll
    for (int j = 0; j < 4; ++j) {
      pm[(sp * 512 + qw) * 16 + g * 4 + j] = mrun[j];
      pl[(sp * 512 + qw) * 16 + g * 4 + j] = lsum[j];
    }
  }
}

// ---------------------------------------------------------------------------
// Kernel 3b: merge 4 split partials. UNCHANGED (verified R5-R14).
// ---------------------------------------------------------------------------
__global__ __launch_bounds__(64) void attn_merge_kernel(
    const float* __restrict__ pacc, const float* __restrict__ pm, const float* __restrict__ pl,
    float* __restrict__ out)
{
  const int qw = blockIdx.x;
  const int b = qw >> 7, q0 = (qw & 127) * 16;
  const int lane = threadIdx.x;

#pragma unroll 1
  for (int row = 0; row < 16; ++row) {
    float m0 = pm[(0 * 512 + qw) * 16 + row], m1 = pm[(1 * 512 + qw) * 16 + row];
    float m2 = pm[(2 * 512 + qw) * 16 + row], m3 = pm[(3 * 512 + qw) * 16 + row];
    float M = fmaxf(fmaxf(m0, m1), fmaxf(m2, m3));
    float w0 = __expf(m0 - M), w1 = __expf(m1 - M), w2 = __expf(m2 - M), w3 = __expf(m3 - M);
    float L = w0 * pl[(0 * 512 + qw) * 16 + row] + w1 * pl[(1 * 512 + qw) * 16 + row] +
              w2 * pl[(2 * 512 + qw) * 16 + row] + w3 * pl[(3 * 512 + qw) * 16 + row];
    float v = w0 * pacc[((size_t)(0 * 512 + qw) * 16 + row) * 64 + lane] +
              w1 * pacc[((size_t)(1 * 512 + qw) * 16 + row) * 64 + lane] +
              w2 * pacc[((size_t)(2 * 512 + qw) * 16 + row) * 64 + lane] +
              w3 * pacc[((size_t)(3 * 512 + qw) * 16 + row) * 64 + lane];
    out[(size_t)(b * S_ + q0 + row) * DK_ + lane] = v / L;
  }
}

// ---------------------------------------------------------------------------
// Kernel 3 (fallback if ws too small): verified single-pass attention.
// ---------------------------------------------------------------------------
__global__ __launch_bounds__(64) void attn_kernel(
    const unsigned short* __restrict__ Qp, const unsigned short* __restrict__ Kp,
    const unsigned short* __restrict__ Vt, const unsigned int* __restrict__ mp,
    float* __restrict__ out)
{
  const int lane = threadIdx.x;
  const int g = lane >> 4, r16 = lane & 15;
  const int qt = blockIdx.x & 127;
  const int b  = blockIdx.x >> 7;
  const int q0 = qt * 16;

  __shared__ __align__(16) unsigned short Kt[64][72];
  __shared__ __align__(16) unsigned short Vs[64][72];
  __shared__ __align__(16) unsigned short Pq[16][72];

  short8 aq0, aq1;
  {
    const unsigned short* qrow = Qp + (size_t)(b * S_ + q0 + r16) * DK_ + g * 8;
    aq0 = *reinterpret_cast<const short8*>(qrow);
    aq1 = *reinterpret_cast<const short8*>(qrow + 32);
  }

  float mrun[4], lsum[4], corr[4];
  f32x4 acc[4];
#pragma unroll
  for (int j = 0; j < 4; ++j) { mrun[j] = -3.0e38f; lsum[j] = 0.f; }
#pragma unroll
  for (int nf = 0; nf < 4; ++nf) { acc[nf].x = 0.f; acc[nf].y = 0.f; acc[nf].z = 0.f; acc[nf].w = 0.f; }

  const int srow_stage = lane >> 3, sgran = lane & 7;

  for (int st = 0; st < 32; ++st) {
    const int s0 = st * 64;
#pragma unroll
    for (int i = 0; i < 8; ++i) {
      int r = i * 8 + srow_stage;
      uint4v kv = *reinterpret_cast<const uint4v*>(Kp + (size_t)(b * S_ + s0 + r) * DK_ + sgran * 8);
      *reinterpret_cast<uint4v*>(&Kt[r][sgran * 8]) = kv;
      uint4v vv = *reinterpret_cast<const uint4v*>(Vt + (size_t)(b * DK_ + r) * S_ + s0 + sgran * 8);
      *reinterpret_cast<uint4v*>(&Vs[r][sgran * 8]) = vv;
    }
    unsigned long long mw[4];
#pragma unroll
    for (int j = 0; j < 4; ++j) {
      size_t widx = ((size_t)(b * S_ + q0 + g * 4 + j) * S_ + s0) >> 5;
      mw[j] = *reinterpret_cast<const unsigned long long*>(mp + widx);
    }
    __syncthreads();

    f32x4 sc[4];
#pragma unroll
    for (int nf = 0; nf < 4; ++nf) { sc[nf].x = 0.f; sc[nf].y = 0.f; sc[nf].z = 0.f; sc[nf].w = 0.f; }
#pragma unroll
    for (int nf = 0; nf < 4; ++nf) {
      short8 bk0 = *reinterpret_cast<const short8*>(&Kt[nf * 16 + r16][g * 8]);
      short8 bk1 = *reinterpret_cast<const short8*>(&Kt[nf * 16 + r16][32 + g * 8]);
      sc[nf] = __builtin_amdgcn_mfma_f32_16x16x32_bf16(aq0, bk0, sc[nf], 0, 0, 0);
      sc[nf] = __builtin_amdgcn_mfma_f32_16x16x32_bf16(aq1, bk1, sc[nf], 0, 0, 0);
    }
#pragma unroll
    for (int nf = 0; nf < 4; ++nf)
#pragma unroll
      for (int j = 0; j < 4; ++j) {
        float v = sc[nf][j] * SCALE_;
        sc[nf][j] = ((mw[j] >> (nf * 16 + r16)) & 1ull) ? 1e-9f : v;
      }
#pragma unroll
    for (int j = 0; j < 4; ++j) {
      float tm = fmaxf(fmaxf(sc[0][j], sc[1][j]), fmaxf(sc[2][j], sc[3][j]));
#pragma unroll
      for (int off = 1; off < 16; off <<= 1) tm = fmaxf(tm, __shfl_xor(tm, off));
      float mn = fmaxf(mrun[j], tm);
      corr[j] = __expf(mrun[j] - mn);
      mrun[j] = mn;
    }
#pragma unroll
    for (int nf = 0; nf < 4; ++nf)
#pragma unroll
      for (int j = 0; j < 4; ++j)
        sc[nf][j] = __expf(sc[nf][j] - mrun[j]);
#pragma unroll
    for (int j = 0; j < 4; ++j) {
      float rs = (sc[0][j] + sc[1][j]) + (sc[2][j] + sc[3][j]);
#pragma unroll
      for (int off = 1; off < 16; off <<= 1) rs += __shfl_xor(rs, off);
      lsum[j] = lsum[j] * corr[j] + rs;
    }
#pragma unroll
    for (int nf = 0; nf < 4; ++nf) {
      acc[nf].x *= corr[0]; acc[nf].y *= corr[1]; acc[nf].z *= corr[2]; acc[nf].w *= corr[3];
    }
#pragma unroll
    for (int nf = 0; nf < 4; ++nf)
#pragma unroll
      for (int j = 0; j < 4; ++j)
        Pq[g * 4 + j][nf * 16 + r16] = f2bf(sc[nf][j]);
    asm volatile("s_waitcnt lgkmcnt(0)" ::: "memory");

#pragma unroll
    for (int k2 = 0; k2 < 2; ++k2) {
      short8 pa = *reinterpret_cast<const short8*>(&Pq[r16][k2 * 32 + g * 8]);
#pragma unroll
      for (int nf = 0; nf < 4; ++nf) {
        short8 bv = *reinterpret_cast<const short8*>(&Vs[nf * 16 + r16][k2 * 32 + g * 8]);
        acc[nf] = __builtin_amdgcn_mfma_f32_16x16x32_bf16(pa, bv, acc[nf], 0, 0, 0);
      }
    }
    __syncthreads();
  }

#pragma unroll
  for (int nf = 0; nf < 4; ++nf)
#pragma unroll
    for (int j = 0; j < 4; ++j)
      out[(size_t)(b * S_ + q0 + g * 4 + j) * DK_ + nf * 16 + r16] = acc[nf][j] / lsum[j];
}

// ---------------------------------------------------------------------------
extern "C" void kernel_launch(void* const* d_in, const int* in_sizes, int n_in,
                              void* d_out, int out_size, void* d_ws, size_t ws_size,
                              hipStream_t stream) {
  const float* q  = (const float*)d_in[0];
  const float* k  = (const float*)d_in[1];
  const float* v  = (const float*)d_in[2];
  const void*  mk = d_in[3];
  const float* wq = (const float*)d_in[4];
  const float* wk = (const float*)d_in[5];
  const float* wv = (const float*)d_in[6];

  char* ws = (char*)d_ws;
  unsigned short* Qp   = (unsigned short*)(ws);                         // 1 MB
  unsigned short* Kp   = (unsigned short*)(ws + (1u << 20));            // 1 MB
  unsigned short* Vt   = (unsigned short*)(ws + (2u << 20));            // 1 MB  [b][dk][s]
  unsigned int*   mp   = (unsigned int*)  (ws + (3u << 20));            // 2 MB packed mask
  unsigned int*   flag = (unsigned int*)  (ws + (5u << 20));            // 4 B
  unsigned short* Wb   = (unsigned short*)(ws + (5u << 20) + 4096);     // 384 KB bf16 weights
  float*          pacc = (float*)(ws + (6u << 20));                     // 8 MB partial acc
  float*          pm   = (float*)(ws + (14u << 20));                    // 128 KB partial m
  float*          pl   = (float*)(ws + (14u << 20) + (1u << 17));       // 128 KB partial l

  wconv_kernel<<<96, 256, 0, stream>>>(wq, wk, wv, Wb);
  detect_kernel<<<1, 64, 0, stream>>>((const unsigned int*)mk, flag);
  maskpack_kernel<<<2048, 256, 0, stream>>>((const unsigned char*)mk, (const unsigned int*)mk, flag, mp);
  proj13_kernel<<<dim3(512, 3), 512, 0, stream>>>(q, k, v, Wb, Qp, Kp, Vt);

  if (ws_size >= (15u << 20)) {
    attn_part_kernel<<<2048, 64, 0, stream>>>(Qp, Kp, Vt, mp, pacc, pm, pl);
    attn_merge_kernel<<<512, 64, 0, stream>>>(pacc, pm, pl, (float*)d_out);
  } else {
    attn_kernel<<<512, 64, 0, stream>>>(Qp, Kp, Vt, mp, (float*)d_out);
  }
}

// Round 16
// 88.929 us; speedup vs baseline: 1.1064x; 1.1064x over previous
//
#include <hip/hip_runtime.h>

// Problem constants
#define B_    4
#define S_    2048
#define DM_   1024
#define DK_   64
#define SCALE_ 0.03125f   // 1024^-0.5  (reference scales by d_model^-0.5, not d_k)

typedef float        f32x4  __attribute__((ext_vector_type(4)));
typedef short        short8 __attribute__((ext_vector_type(8)));
typedef float        fltx4  __attribute__((ext_vector_type(4)));
typedef unsigned int uint2v __attribute__((ext_vector_type(2)));
typedef unsigned int uint4v __attribute__((ext_vector_type(4)));

// fp32 -> bf16, round-to-nearest-even
static __device__ __forceinline__ unsigned short f2bf(float f) {
  unsigned u = __float_as_uint(f);
  u += 0x7fffu + ((u >> 16) & 1u);
  return (unsigned short)(u >> 16);
}
static __device__ __forceinline__ uint2v pack4(float a, float b, float c, float d) {
  uint2v r;
  r.x = (unsigned)f2bf(a) | ((unsigned)f2bf(b) << 16);
  r.y = (unsigned)f2bf(c) | ((unsigned)f2bf(d) << 16);
  return r;
}

// ---------------------------------------------------------------------------
// Kernel 0: detect mask element width (int32 of {0,1} vs byte-packed bools).
// ---------------------------------------------------------------------------
__global__ void detect_kernel(const unsigned int* __restrict__ m, unsigned int* __restrict__ flag) {
  unsigned v = m[threadIdx.x];
  unsigned long long bad = __ballot(v > 1u);
  if (threadIdx.x == 0) flag[0] = (bad != 0ull) ? 1u : 0u;
}

// ---------------------------------------------------------------------------
// Kernel W: convert the 3 weight matrices to bf16 once. Wb: [which][64][1024].
// ---------------------------------------------------------------------------
__global__ __launch_bounds__(256) void wconv_kernel(
    const float* __restrict__ wq, const float* __restrict__ wk, const float* __restrict__ wv,
    unsigned short* __restrict__ Wb)
{
  const int idx   = blockIdx.x * 256 + threadIdx.x;
  const int which = idx >> 13;
  const int e     = idx & 8191;
  const float* __restrict__ w = (which == 0) ? wq : (which == 1) ? wk : wv;
  fltx4 v0 = *reinterpret_cast<const fltx4*>(w + (size_t)e * 8);
  fltx4 v1 = *reinterpret_cast<const fltx4*>(w + (size_t)e * 8 + 4);
  uint4v o;
  o.x = (unsigned)f2bf(v0.x) | ((unsigned)f2bf(v0.y) << 16);
  o.y = (unsigned)f2bf(v0.z) | ((unsigned)f2bf(v0.w) << 16);
  o.z = (unsigned)f2bf(v1.x) | ((unsigned)f2bf(v1.y) << 16);
  o.w = (unsigned)f2bf(v1.z) | ((unsigned)f2bf(v1.w) << 16);
  *reinterpret_cast<uint4v*>(Wb + (size_t)which * 65536 + (size_t)e * 8) = o;
}

// ---------------------------------------------------------------------------
// Kernel 1: pack mask to 1 bit/element (2 MB, L2-hot). Verified R2-T3.
// ---------------------------------------------------------------------------
__global__ __launch_bounds__(256) void maskpack_kernel(const unsigned char* __restrict__ mb,
                                                       const unsigned int* __restrict__ mi,
                                                       const unsigned int* __restrict__ flag,
                                                       unsigned int* __restrict__ mp) {
  const int w = blockIdx.x * 256 + threadIdx.x;
  unsigned out = 0;
  if (flag[0]) {
    const uint4v* p = reinterpret_cast<const uint4v*>(mb + (size_t)w * 32);
    uint4v a = p[0], b = p[1];
    unsigned ws0[8];
    ws0[0]=a.x; ws0[1]=a.y; ws0[2]=a.z; ws0[3]=a.w; ws0[4]=b.x; ws0[5]=b.y; ws0[6]=b.z; ws0[7]=b.w;
#pragma unroll
    for (int i = 0; i < 8; ++i) {
      unsigned v = ws0[i];
      out |= ((v & 0x000000ffu) ? 1u : 0u) << (i * 4 + 0);
      out |= ((v & 0x0000ff00u) ? 1u : 0u) << (i * 4 + 1);
      out |= ((v & 0x00ff0000u) ? 1u : 0u) << (i * 4 + 2);
      out |= ((v & 0xff000000u) ? 1u : 0u) << (i * 4 + 3);
    }
  } else {
    const uint4v* p = reinterpret_cast<const uint4v*>(mi + (size_t)w * 32);
#pragma unroll
    for (int i = 0; i < 8; ++i) {
      uint4v a = p[i];
      out |= (a.x ? 1u : 0u) << (i * 4 + 0);
      out |= (a.y ? 1u : 0u) << (i * 4 + 1);
      out |= (a.z ? 1u : 0u) << (i * 4 + 2);
      out |= (a.w ? 1u : 0u) << (i * 4 + 3);
    }
  }
  mp[w] = out;
}

// ---------------------------------------------------------------------------
// Kernel 2 (v14): proj13 template + 4-tile W amortization.
// R15 model: duration = logical bytes / ~6.3 TB/s request-path ceiling.
// proj13 moved 295 MB (X 100 + W re-reads 196). proj14: each block does
// FOUR sequential 16-row tiles; each wave hoists its 16 W fragments into
// registers ONCE (static indices) and reuses them across tiles -> W 48 MB,
// total 148 MB. Per-tile body is proj13 VERBATIM (stage -> sync -> MFMA ->
// red-write -> sync -> reduce/store; race-free: red reads of tile t and
// red writes of tile t+1 are separated by tile t+1's stage barrier).
//   D[m=g*4+j][n=cgrp*16+r16] (T1-verified layout)
// ---------------------------------------------------------------------------
__global__ __launch_bounds__(512) void proj14_kernel(
    const float* __restrict__ xq, const float* __restrict__ xk, const float* __restrict__ xv,
    const unsigned short* __restrict__ Wb,
    unsigned short* __restrict__ Qp, unsigned short* __restrict__ Kp, unsigned short* __restrict__ Vt)
{
  const int which = blockIdx.y;
  const float* __restrict__ x = (which == 0) ? xq : (which == 1) ? xk : xv;
  const int tid = threadIdx.x, wid = tid >> 6;
  const int lane = tid & 63, g = lane >> 4, r16 = lane & 15;
  const int cgrp = wid >> 1, khalf = wid & 1;

  __shared__ __align__(16) unsigned short Xb[16 * 1024];   // [16 rows][1024 bf16], pitch 2048 B, swizzled
  __shared__ __align__(16) f32x4 red[4][2][64];            // [cgrp][khalf][lane], 8 KB

  // ---- hoist: this wave's 16 W fragments (rows cgrp*16+r16, its K-half) ----
  const unsigned short* __restrict__ wb =
      Wb + (size_t)which * 65536 + (size_t)(cgrp * 16 + r16) * DM_ + khalf * 512 + g * 8;
  short8 w[16];
#pragma unroll
  for (int kc = 0; kc < 16; ++kc)
    w[kc] = *reinterpret_cast<const short8*>(wb + kc * 32);

  for (int t = 0; t < 4; ++t) {
    const int row0 = blockIdx.x * 64 + t * 16;

    // ---- phase 1: stream the 16x1024 f32 tile (64 KB), 8 loads/thread ----
#pragma unroll
    for (int i = 0; i < 8; ++i) {
      const int fi   = i * 2048 + tid * 4;
      const int row  = fi >> 10;
      const int colf = fi & 1023;
      fltx4 v = *reinterpret_cast<const fltx4*>(x + (size_t)(row0 + row) * DM_ + colf);
      const int cb   = colf * 2;
      const int addr = row * 2048 + (cb ^ ((row & 15) << 4));
      *reinterpret_cast<uint2v*>((char*)Xb + addr) = pack4(v.x, v.y, v.z, v.w);
    }
    __syncthreads();   // Xb ready; prior tile's red reads already done

    // ---- phase 2: 16 MFMAs over this wave's K-half with RESIDENT W ----
    f32x4 acc; acc.x = 0.f; acc.y = 0.f; acc.z = 0.f; acc.w = 0.f;
#pragma unroll
    for (int kc = 0; kc < 16; ++kc) {
      const int cb = khalf * 1024 + kc * 64 + g * 16;
      const int ra = r16 * 2048 + (cb ^ ((r16 & 15) << 4));
      short8 a = *reinterpret_cast<const short8*>((const char*)Xb + ra);
      acc = __builtin_amdgcn_mfma_f32_16x16x32_bf16(a, w[kc], acc, 0, 0, 0);
    }

    // ---- K-half reduction (proj13-verified pattern) ----
    red[cgrp][khalf][lane] = acc;
    __syncthreads();   // red ready; Xb reads done -> next stage safe

    if (wid < 4) {
      f32x4 a0 = red[wid][0][lane];
      f32x4 a1 = red[wid][1][lane];
      f32x4 s; s.x = a0.x + a1.x; s.y = a0.y + a1.y; s.z = a0.z + a1.z; s.w = a0.w + a1.w;
      if (which < 2) {
        unsigned short* __restrict__ dst = (which == 0) ? Qp : Kp;
#pragma unroll
        for (int j = 0; j < 4; ++j)
          dst[(size_t)(row0 + g * 4 + j) * DK_ + wid * 16 + r16] = f2bf(s[j]);
      } else {
        const int grow = row0 + g * 4;
        const int bb = grow >> 11, sin = grow & 2047;
        *reinterpret_cast<uint2v*>(Vt + (size_t)(bb * DK_ + wid * 16 + r16) * S_ + sin) =
            pack4(s.x, s.y, s.z, s.w);
      }
    }
  }
}

// ---------------------------------------------------------------------------
// Kernel 3a: flash attention PARTIAL (split-S x4). EXACT R8-R15 body (verified).
// ---------------------------------------------------------------------------
__global__ __launch_bounds__(64) void attn_part_kernel(
    const unsigned short* __restrict__ Qp, const unsigned short* __restrict__ Kp,
    const unsigned short* __restrict__ Vt, const unsigned int* __restrict__ mp,
    float* __restrict__ pacc, float* __restrict__ pm, float* __restrict__ pl)
{
  const int lane = threadIdx.x;
  const int g = lane >> 4, r16 = lane & 15;
  const int bx = blockIdx.x;
  const int sp = bx >> 9;
  const int qw = bx & 511;
  const int b  = qw >> 7;
  const int q0 = (qw & 127) * 16;

  __shared__ __align__(16) unsigned short Kt[64][72];
  __shared__ __align__(16) unsigned short Vs[64][72];
  __shared__ __align__(16) unsigned short Pq[16][72];

  short8 aq0, aq1;
  {
    const unsigned short* qrow = Qp + (size_t)(b * S_ + q0 + r16) * DK_ + g * 8;
    aq0 = *reinterpret_cast<const short8*>(qrow);
    aq1 = *reinterpret_cast<const short8*>(qrow + 32);
  }

  float mrun[4], lsum[4], corr[4];
  f32x4 acc[4];
#pragma unroll
  for (int j = 0; j < 4; ++j) { mrun[j] = -3.0e38f; lsum[j] = 0.f; }
#pragma unroll
  for (int nf = 0; nf < 4; ++nf) { acc[nf].x = 0.f; acc[nf].y = 0.f; acc[nf].z = 0.f; acc[nf].w = 0.f; }

  const int srow_stage = lane >> 3, sgran = lane & 7;

  for (int st = sp * 8; st < sp * 8 + 8; ++st) {
    const int s0 = st * 64;
#pragma unroll
    for (int i = 0; i < 8; ++i) {
      int r = i * 8 + srow_stage;
      uint4v kv = *reinterpret_cast<const uint4v*>(Kp + (size_t)(b * S_ + s0 + r) * DK_ + sgran * 8);
      *reinterpret_cast<uint4v*>(&Kt[r][sgran * 8]) = kv;
      uint4v vv = *reinterpret_cast<const uint4v*>(Vt + (size_t)(b * DK_ + r) * S_ + s0 + sgran * 8);
      *reinterpret_cast<uint4v*>(&Vs[r][sgran * 8]) = vv;
    }
    unsigned long long mw[4];
#pragma unroll
    for (int j = 0; j < 4; ++j) {
      size_t widx = ((size_t)(b * S_ + q0 + g * 4 + j) * S_ + s0) >> 5;
      mw[j] = *reinterpret_cast<const unsigned long long*>(mp + widx);
    }
    __syncthreads();

    f32x4 sc[4];
#pragma unroll
    for (int nf = 0; nf < 4; ++nf) { sc[nf].x = 0.f; sc[nf].y = 0.f; sc[nf].z = 0.f; sc[nf].w = 0.f; }
#pragma unroll
    for (int nf = 0; nf < 4; ++nf) {
      short8 bk0 = *reinterpret_cast<const short8*>(&Kt[nf * 16 + r16][g * 8]);
      short8 bk1 = *reinterpret_cast<const short8*>(&Kt[nf * 16 + r16][32 + g * 8]);
      sc[nf] = __builtin_amdgcn_mfma_f32_16x16x32_bf16(aq0, bk0, sc[nf], 0, 0, 0);
      sc[nf] = __builtin_amdgcn_mfma_f32_16x16x32_bf16(aq1, bk1, sc[nf], 0, 0, 0);
    }
#pragma unroll
    for (int nf = 0; nf < 4; ++nf)
#pragma unroll
      for (int j = 0; j < 4; ++j) {
        float v = sc[nf][j] * SCALE_;
        sc[nf][j] = ((mw[j] >> (nf * 16 + r16)) & 1ull) ? 1e-9f : v;
      }
#pragma unroll
    for (int j = 0; j < 4; ++j) {
      float tm = fmaxf(fmaxf(sc[0][j], sc[1][j]), fmaxf(sc[2][j], sc[3][j]));
#pragma unroll
      for (int off = 1; off < 16; off <<= 1) tm = fmaxf(tm, __shfl_xor(tm, off));
      float mn = fmaxf(mrun[j], tm);
      corr[j] = __expf(mrun[j] - mn);
      mrun[j] = mn;
    }
#pragma unroll
    for (int nf = 0; nf < 4; ++nf)
#pragma unroll
      for (int j = 0; j < 4; ++j)
        sc[nf][j] = __expf(sc[nf][j] - mrun[j]);
#pragma unroll
    for (int j = 0; j < 4; ++j) {
      float rs = (sc[0][j] + sc[1][j]) + (sc[2][j] + sc[3][j]);
#pragma unroll
      for (int off = 1; off < 16; off <<= 1) rs += __shfl_xor(rs, off);
      lsum[j] = lsum[j] * corr[j] + rs;
    }
#pragma unroll
    for (int nf = 0; nf < 4; ++nf) {
      acc[nf].x *= corr[0]; acc[nf].y *= corr[1]; acc[nf].z *= corr[2]; acc[nf].w *= corr[3];
    }
#pragma unroll
    for (int nf = 0; nf < 4; ++nf)
#pragma unroll
      for (int j = 0; j < 4; ++j)
        Pq[g * 4 + j][nf * 16 + r16] = f2bf(sc[nf][j]);
    asm volatile("s_waitcnt lgkmcnt(0)" ::: "memory");

#pragma unroll
    for (int k2 = 0; k2 < 2; ++k2) {
      short8 pa = *reinterpret_cast<const short8*>(&Pq[r16][k2 * 32 + g * 8]);
#pragma unroll
      for (int nf = 0; nf < 4; ++nf) {
        short8 bv = *reinterpret_cast<const short8*>(&Vs[nf * 16 + r16][k2 * 32 + g * 8]);
        acc[nf] = __builtin_amdgcn_mfma_f32_16x16x32_bf16(pa, bv, acc[nf], 0, 0, 0);
      }
    }
    __syncthreads();
  }

  float* __restrict__ pa = pacc + (size_t)(sp * 512 + qw) * 1024;
#pragma unroll
  for (int nf = 0; nf < 4; ++nf)
#pragma unroll
    for (int j = 0; j < 4; ++j)
      pa[(g * 4 + j) * 64 + nf * 16 + r16] = acc[nf][j];
  if (r16 == 0) {
#pragma unroll
    for (int j = 0; j < 4; ++j) {
      pm[(sp * 512 + qw) * 16 + g * 4 + j] = mrun[j];
      pl[(sp * 512 + qw) * 16 + g * 4 + j] = lsum[j];
    }
  }
}

// ---------------------------------------------------------------------------
// Kernel 3b: merge 4 split partials. UNCHANGED (verified R5-R15).
// ---------------------------------------------------------------------------
__global__ __launch_bounds__(64) void attn_merge_kernel(
    const float* __restrict__ pacc, const float* __restrict__ pm, const float* __restrict__ pl,
    float* __restrict__ out)
{
  const int qw = blockIdx.x;
  const int b = qw >> 7, q0 = (qw & 127) * 16;
  const int lane = threadIdx.x;

#pragma unroll 1
  for (int row = 0; row < 16; ++row) {
    float m0 = pm[(0 * 512 + qw) * 16 + row], m1 = pm[(1 * 512 + qw) * 16 + row];
    float m2 = pm[(2 * 512 + qw) * 16 + row], m3 = pm[(3 * 512 + qw) * 16 + row];
    float M = fmaxf(fmaxf(m0, m1), fmaxf(m2, m3));
    float w0 = __expf(m0 - M), w1 = __expf(m1 - M), w2 = __expf(m2 - M), w3 = __expf(m3 - M);
    float L = w0 * pl[(0 * 512 + qw) * 16 + row] + w1 * pl[(1 * 512 + qw) * 16 + row] +
              w2 * pl[(2 * 512 + qw) * 16 + row] + w3 * pl[(3 * 512 + qw) * 16 + row];
    float v = w0 * pacc[((size_t)(0 * 512 + qw) * 16 + row) * 64 + lane] +
              w1 * pacc[((size_t)(1 * 512 + qw) * 16 + row) * 64 + lane] +
              w2 * pacc[((size_t)(2 * 512 + qw) * 16 + row) * 64 + lane] +
              w3 * pacc[((size_t)(3 * 512 + qw) * 16 + row) * 64 + lane];
    out[(size_t)(b * S_ + q0 + row) * DK_ + lane] = v / L;
  }
}

// ---------------------------------------------------------------------------
// Kernel 3 (fallback if ws too small): verified single-pass attention.
// ---------------------------------------------------------------------------
__global__ __launch_bounds__(64) void attn_kernel(
    const unsigned short* __restrict__ Qp, const unsigned short* __restrict__ Kp,
    const unsigned short* __restrict__ Vt, const unsigned int* __restrict__ mp,
    float* __restrict__ out)
{
  const int lane = threadIdx.x;
  const int g = lane >> 4, r16 = lane & 15;
  const int qt = blockIdx.x & 127;
  const int b  = blockIdx.x >> 7;
  const int q0 = qt * 16;

  __shared__ __align__(16) unsigned short Kt[64][72];
  __shared__ __align__(16) unsigned short Vs[64][72];
  __shared__ __align__(16) unsigned short Pq[16][72];

  short8 aq0, aq1;
  {
    const unsigned short* qrow = Qp + (size_t)(b * S_ + q0 + r16) * DK_ + g * 8;
    aq0 = *reinterpret_cast<const short8*>(qrow);
    aq1 = *reinterpret_cast<const short8*>(qrow + 32);
  }

  float mrun[4], lsum[4], corr[4];
  f32x4 acc[4];
#pragma unroll
  for (int j = 0; j < 4; ++j) { mrun[j] = -3.0e38f; lsum[j] = 0.f; }
#pragma unroll
  for (int nf = 0; nf < 4; ++nf) { acc[nf].x = 0.f; acc[nf].y = 0.f; acc[nf].z = 0.f; acc[nf].w = 0.f; }

  const int srow_stage = lane >> 3, sgran = lane & 7;

  for (int st = 0; st < 32; ++st) {
    const int s0 = st * 64;
#pragma unroll
    for (int i = 0; i < 8; ++i) {
      int r = i * 8 + srow_stage;
      uint4v kv = *reinterpret_cast<const uint4v*>(Kp + (size_t)(b * S_ + s0 + r) * DK_ + sgran * 8);
      *reinterpret_cast<uint4v*>(&Kt[r][sgran * 8]) = kv;
      uint4v vv = *reinterpret_cast<const uint4v*>(Vt + (size_t)(b * DK_ + r) * S_ + s0 + sgran * 8);
      *reinterpret_cast<uint4v*>(&Vs[r][sgran * 8]) = vv;
    }
    unsigned long long mw[4];
#pragma unroll
    for (int j = 0; j < 4; ++j) {
      size_t widx = ((size_t)(b * S_ + q0 + g * 4 + j) * S_ + s0) >> 5;
      mw[j] = *reinterpret_cast<const unsigned long long*>(mp + widx);
    }
    __syncthreads();

    f32x4 sc[4];
#pragma unroll
    for (int nf = 0; nf < 4; ++nf) { sc[nf].x = 0.f; sc[nf].y = 0.f; sc[nf].z = 0.f; sc[nf].w = 0.f; }
#pragma unroll
    for (int nf = 0; nf < 4; ++nf) {
      short8 bk0 = *reinterpret_cast<const short8*>(&Kt[nf * 16 + r16][g * 8]);
      short8 bk1 = *reinterpret_cast<const short8*>(&Kt[nf * 16 + r16][32 + g * 8]);
      sc[nf] = __builtin_amdgcn_mfma_f32_16x16x32_bf16(aq0, bk0, sc[nf], 0, 0, 0);
      sc[nf] = __builtin_amdgcn_mfma_f32_16x16x32_bf16(aq1, bk1, sc[nf], 0, 0, 0);
    }
#pragma unroll
    for (int nf = 0; nf < 4; ++nf)
#pragma unroll
      for (int j = 0; j < 4; ++j) {
        float v = sc[nf][j] * SCALE_;
        sc[nf][j] = ((mw[j] >> (nf * 16 + r16)) & 1ull) ? 1e-9f : v;
      }
#pragma unroll
    for (int j = 0; j < 4; ++j) {
      float tm = fmaxf(fmaxf(sc[0][j], sc[1][j]), fmaxf(sc[2][j], sc[3][j]));
#pragma unroll
      for (int off = 1; off < 16; off <<= 1) tm = fmaxf(tm, __shfl_xor(tm, off));
      float mn = fmaxf(mrun[j], tm);
      corr[j] = __expf(mrun[j] - mn);
      mrun[j] = mn;
    }
#pragma unroll
    for (int nf = 0; nf < 4; ++nf)
#pragma unroll
      for (int j = 0; j < 4; ++j)
        sc[nf][j] = __expf(sc[nf][j] - mrun[j]);
#pragma unroll
    for (int j = 0; j < 4; ++j) {
      float rs = (sc[0][j] + sc[1][j]) + (sc[2][j] + sc[3][j]);
#pragma unroll
      for (int off = 1; off < 16; off <<= 1) rs += __shfl_xor(rs, off);
      lsum[j] = lsum[j] * corr[j] + rs;
    }
#pragma unroll
    for (int nf = 0; nf < 4; ++nf) {
      acc[nf].x *= corr[0]; acc[nf].y *= corr[1]; acc[nf].z *= corr[2]; acc[nf].w *= corr[3];
    }
#pragma unroll
    for (int nf = 0; nf < 4; ++nf)
#pragma unroll
      for (int j = 0; j < 4; ++j)
        Pq[g * 4 + j][nf * 16 + r16] = f2bf(sc[nf][j]);
    asm volatile("s_waitcnt lgkmcnt(0)" ::: "memory");

#pragma unroll
    for (int k2 = 0; k2 < 2; ++k2) {
      short8 pa = *reinterpret_cast<const short8*>(&Pq[r16][k2 * 32 + g * 8]);
#pragma unroll
      for (int nf = 0; nf < 4; ++nf) {
        short8 bv = *reinterpret_cast<const short8*>(&Vs[nf * 16 + r16][k2 * 32 + g * 8]);
        acc[nf] = __builtin_amdgcn_mfma_f32_16x16x32_bf16(pa, bv, acc[nf], 0, 0, 0);
      }
    }
    __syncthreads();
  }

#pragma unroll
  for (int nf = 0; nf < 4; ++nf)
#pragma unroll
    for (int j = 0; j < 4; ++j)
      out[(size_t)(b * S_ + q0 + g * 4 + j) * DK_ + nf * 16 + r16] = acc[nf][j] / lsum[j];
}

// ---------------------------------------------------------------------------
extern "C" void kernel_launch(void* const* d_in, const int* in_sizes, int n_in,
                              void* d_out, int out_size, void* d_ws, size_t ws_size,
                              hipStream_t stream) {
  const float* q  = (const float*)d_in[0];
  const float* k  = (const float*)d_in[1];
  const float* v  = (const float*)d_in[2];
  const void*  mk = d_in[3];
  const float* wq = (const float*)d_in[4];
  const float* wk = (const float*)d_in[5];
  const float* wv = (const float*)d_in[6];

  char* ws = (char*)d_ws;
  unsigned short* Qp   = (unsigned short*)(ws);                         // 1 MB
  unsigned short* Kp   = (unsigned short*)(ws + (1u << 20));            // 1 MB
  unsigned short* Vt   = (unsigned short*)(ws + (2u << 20));            // 1 MB  [b][dk][s]
  unsigned int*   mp   = (unsigned int*)  (ws + (3u << 20));            // 2 MB packed mask
  unsigned int*   flag = (unsigned int*)  (ws + (5u << 20));            // 4 B
  unsigned short* Wb   = (unsigned short*)(ws + (5u << 20) + 4096);     // 384 KB bf16 weights
  float*          pacc = (float*)(ws + (6u << 20));                     // 8 MB partial acc
  float*          pm   = (float*)(ws + (14u << 20));                    // 128 KB partial m
  float*          pl   = (float*)(ws + (14u << 20) + (1u << 17));       // 128 KB partial l

  wconv_kernel<<<96, 256, 0, stream>>>(wq, wk, wv, Wb);
  detect_kernel<<<1, 64, 0, stream>>>((const unsigned int*)mk, flag);
  maskpack_kernel<<<2048, 256, 0, stream>>>((const unsigned char*)mk, (const unsigned int*)mk, flag, mp);
  proj14_kernel<<<dim3(128, 3), 512, 0, stream>>>(q, k, v, Wb, Qp, Kp, Vt);

  if (ws_size >= (15u << 20)) {
    attn_part_kernel<<<2048, 64, 0, stream>>>(Qp, Kp, Vt, mp, pacc, pm, pl);
    attn_merge_kernel<<<512, 64, 0, stream>>>(pacc, pm, pl, (float*)d_out);
  } else {
    attn_kernel<<<512, 64, 0, stream>>>(Qp, Kp, Vt, mp, (float*)d_out);
  }
}